// Round 9
// baseline (161.054 us; speedup 1.0000x reference)
//
#include <hip/hip_runtime.h>

#define B_  8
#define QL_ 128
#define ML_ 1024
#define KS_ 512
#define H_  256

// ws layout (floats):
//   Eq (h-PERMUTED) [B][QL][H]            @ 0        (262144)
//   Ek (h-PERMUTED) [B][ML][H]            @ 262144   (2097152)
//   mask canonical uint8 [B*ML]           @ 2359296  (2048 float slots)
//   Whi bf16 [512][512]                   @ 2361344  (131072)
//   Wlo bf16 [512][512]                   @ 2492416  (131072)
//   MThi bf16 [8][512][1024] (memory^T)   @ 2623488  (2097152)
//   MTlo bf16 [8][512][1024]              @ 4720640  (2097152)
//   Wbhi bf16 [8][128][1024] (weights)    @ 6817792  (524288)
//   Wblo bf16 [8][128][1024]              @ 7342080  (524288)
//   Xhi bf16 [9216][512] (query|memory)   @ 7866368  (2359296)
//   Xlo bf16 [9216][512]                  @ 10225664 (2359296)
//   wlp (h-PERMUTED wl) [256]             @ 12584960 (256)
// h-permutation (within each 8-group): orig o -> ((o&3)<<1)|(o>>2): pairs are
// (h_j, h_{j+4}) -> packed-f32 (v_pk_fma_f32) processing of 2 rcp-quads.
#define QP_OFF 0
#define KP_OFF 262144
#define MASK_OFF 2359296
#define WH_OFF 2361344
#define WL_OFF 2492416
#define MT_H_OFF 2623488
#define MT_L_OFF 4720640
#define WB_H_OFF 6817792
#define WB_L_OFF 7342080
#define XH_OFF 7866368
#define XL_OFF 10225664
#define WLP_OFF 12584960

typedef __attribute__((ext_vector_type(8))) short bfrag;   // 8 bf16 (4 VGPR)
typedef __attribute__((ext_vector_type(4))) float f4acc;   // MFMA acc
typedef __attribute__((ext_vector_type(2))) float f2;      // packed f32 pair

// fp32 -> (hi,lo) bf16 split. hi = truncation (residual <= 2^-8|x|, captured
// exactly by fp32 subtract); lo = RNE of residual (final err <= 2^-17|x|).
__device__ __forceinline__ void split1(float v, unsigned& h, unsigned& lo) {
    unsigned u  = __float_as_uint(v);
    unsigned hb = u & 0xFFFF0000u;
    float    lf = v - __uint_as_float(hb);           // exact
    unsigned ul = __float_as_uint(lf);
    unsigned lr = ul + 0x7FFFu + ((ul >> 16) & 1u);  // RNE
    h  = u >> 16;
    lo = lr >> 16;
}

__device__ __forceinline__ void split4(const float4& a, unsigned& h01, unsigned& h23,
                                       unsigned& l01, unsigned& l23) {
    unsigned h[4], l[4];
    split1(a.x, h[0], l[0]); split1(a.y, h[1], l[1]);
    split1(a.z, h[2], l[2]); split1(a.w, h[3], l[3]);
    h01 = h[0] | (h[1] << 16); h23 = h[2] | (h[3] << 16);
    l01 = l[0] | (l[1] << 16); l23 = l[2] | (l[3] << 16);
}

// ---------------------------------------------------------------------------
// Prep kernel, grid 2241 x 256 (R7 arrangement — R8's MT-to-softmax move was
// neutral-to-negative, reverted):
//   bid 0..63     : W split (Wq rows 0..255, Wk rows 256..511 of Whi/Wlo)
//   bid 64..191   : query  -> Xhi/Xlo rows 0..1023
//   bid 192..1215 : memory -> Xhi/Xlo rows 1024..9215
//   bid 1216..2239: memory transpose-split -> MThi/MTlo[b][s][m]
//   bid 2240      : mask canonicalizer + permuted-wl copy
// ---------------------------------------------------------------------------
__global__ __launch_bounds__(256) void prep_kernel(
    const float* __restrict__ query, const float* __restrict__ memory,
    const float* __restrict__ Wq, const float* __restrict__ Wk,
    const float* __restrict__ wl,
    unsigned short* __restrict__ Whi, unsigned short* __restrict__ Wlo,
    unsigned short* __restrict__ Xhi, unsigned short* __restrict__ Xlo,
    unsigned short* __restrict__ MThi, unsigned short* __restrict__ MTlo,
    const unsigned char* __restrict__ mraw, unsigned char* __restrict__ mout,
    float* __restrict__ wlp) {
    const int bid = blockIdx.x;
    const int t = threadIdx.x;

    if (bid == 2240) {   // ---- mask canonicalizer + wl permute ----
        wlp[(t & ~7) | (((t & 3) << 1) | ((t >> 2) & 1))] = wl[t];
        __shared__ int s_not01, s_not0f;
        const unsigned int* w = (const unsigned int*)mraw;
        if (t == 0) { s_not01 = 0; s_not0f = 0; }
        __syncthreads();
        int not01 = 0, not0f = 0;
        for (int i = t; i < 2048; i += 256) {
            unsigned int v = w[i];
            if (v != 0u && v != 1u) not01 = 1;
            if (v != 0u && v != 0x3F800000u) not0f = 1;
        }
        if (not01) atomicOr(&s_not01, 1);
        if (not0f) atomicOr(&s_not0f, 1);
        __syncthreads();
        int wordTyped = (!s_not01) || (!s_not0f);
        for (int i = t; i < B_ * ML_; i += 256) {
            unsigned char mv;
            if (wordTyped) mv = (w[i] != 0u) ? 1 : 0;
            else           mv = mraw[i] ? 1 : 0;
            mout[i] = mv;
        }
        return;
    }

    if (bid >= 1216) {   // ---- memory transpose-split (64x64 tile via LDS) ----
        const int idx = bid - 1216;     // 0..1023
        const int b  = idx >> 7;
        const int r  = idx & 127;
        const int mt = r >> 3;
        const int st = r & 7;
        __shared__ float T[64][68];

        const int i  = t >> 2, jb = (t & 3) << 4;
        const float* mp = memory + ((size_t)(b * ML_ + mt * 64 + i)) * KS_ + st * 64 + jb;
#pragma unroll
        for (int q = 0; q < 4; ++q)
            *(float4*)(&T[i][jb + q * 4]) = *(const float4*)(mp + q * 4);
        __syncthreads();

        const int s = t >> 2, mb = (t & 3) << 4;
        unsigned hh[16], ll[16];
#pragma unroll
        for (int e = 0; e < 16; ++e) split1(T[mb + e][s], hh[e], ll[e]);
        unsigned hp[8], lp[8];
#pragma unroll
        for (int e = 0; e < 8; ++e) {
            hp[e] = hh[2 * e] | (hh[2 * e + 1] << 16);
            lp[e] = ll[2 * e] | (ll[2 * e + 1] << 16);
        }
        const size_t doff = ((size_t)(b * KS_ + st * 64 + s)) * ML_ + mt * 64 + mb;
        *(uint4*)(MThi + doff)     = make_uint4(hp[0], hp[1], hp[2], hp[3]);
        *(uint4*)(MThi + doff + 8) = make_uint4(hp[4], hp[5], hp[6], hp[7]);
        *(uint4*)(MTlo + doff)     = make_uint4(lp[0], lp[1], lp[2], lp[3]);
        *(uint4*)(MTlo + doff + 8) = make_uint4(lp[4], lp[5], lp[6], lp[7]);
        return;
    }

    // ---- linear hi/lo splits: W planes and X planes ----
    const float* src; unsigned short *dh, *dl; size_t soff, doff;
    if (bid < 64) {
        src = (bid < 32) ? Wq : Wk;
        soff = (size_t)(bid & 31) * 4096;
        doff = ((bid < 32) ? 0 : 131072) + soff;
        dh = Whi; dl = Wlo;
    } else if (bid < 192) {
        src = query;  soff = (size_t)(bid - 64) * 4096;  doff = soff;
        dh = Xhi; dl = Xlo;
    } else {
        src = memory; soff = (size_t)(bid - 192) * 4096; doff = 524288 + soff;
        dh = Xhi; dl = Xlo;
    }
    soff += (size_t)t * 16; doff += (size_t)t * 16;

    unsigned hw[8], lw[8];
#pragma unroll
    for (int i = 0; i < 4; ++i) {
        float4 v = *(const float4*)(src + soff + i * 4);
        split4(v, hw[i * 2], hw[i * 2 + 1], lw[i * 2], lw[i * 2 + 1]);
    }
    *(uint4*)(dh + doff)     = make_uint4(hw[0], hw[1], hw[2], hw[3]);
    *(uint4*)(dh + doff + 8) = make_uint4(hw[4], hw[5], hw[6], hw[7]);
    *(uint4*)(dl + doff)     = make_uint4(lw[0], lw[1], lw[2], lw[3]);
    *(uint4*)(dl + doff + 8) = make_uint4(lw[4], lw[5], lw[6], lw[7]);
}

// ---------------------------------------------------------------------------
// Projection via bf16x3-split MFMA — UNCHANGED (validated in R7's −9 us win).
// attn_out-style schedule: pre-split operands, BK=64, 1 barrier/chunk,
// reg-prefetch 2 chunks ahead, XOR-swizzled LDS. Stores h-PERMUTED Eq/Ek.
// ---------------------------------------------------------------------------
__global__ __launch_bounds__(256) void proj_kernel(
    const unsigned short* __restrict__ Xhi, const unsigned short* __restrict__ Xlo,
    const unsigned short* __restrict__ Whi, const unsigned short* __restrict__ Wlo,
    const float* __restrict__ bq, const float* __restrict__ bk,
    float* __restrict__ Eq, float* __restrict__ Ek) {
    const int bid = blockIdx.x;
    const int t = threadIdx.x;
    const int wk = (bid & 7) * 144 + (bid >> 3);   // XCD-chunked (1152 = 8*144)
    const int nt = wk & 3;
    const int mt = wk >> 2;          // 0..287

    const bool isQ = (mt < 32);
    const int arow0 = mt * 32;
    const int orow0 = isQ ? arow0 : arow0 - 1024;
    const float* bias = isQ ? bq : bk;
    float* out = isQ ? Eq : Ek;
    const int wrb = (isQ ? 0 : 256) + nt * 64;

    const int w  = t >> 6;
    const int wm = w >> 1, wn = w & 1;   // wave = 16m x 32n
    const int l  = t & 63;
    const int lr = l & 15, lk = l >> 4;

    __shared__ unsigned short As[2][2][32][64];   // [buf][plane][row][k]
    __shared__ unsigned short Bs[2][2][64][64];

    const int pa   = t >> 7;
    const int slot = t & 127;
    const int arow = slot >> 2, ao = slot & 3;
    const int brow = slot >> 1, bo0 = (slot & 1) * 4;
    const unsigned short* asrc = (pa ? Xlo : Xhi) + (size_t)(arow0 + arow) * 512 + ao * 8;
    const unsigned short* bsrc = (pa ? Wlo : Whi) + (size_t)(wrb + brow) * 512 + bo0 * 8;
    const int awd0 = (ao ^ (arow & 7)) * 8;
    const int awd1 = ((ao + 4) ^ (arow & 7)) * 8;
    int bwd[4];
#pragma unroll
    for (int i = 0; i < 4; ++i) bwd[i] = ((bo0 + i) ^ (brow & 7)) * 8;

    f4acc acc[2];
    acc[0] = (f4acc){0.f, 0.f, 0.f, 0.f};
    acc[1] = (f4acc){0.f, 0.f, 0.f, 0.f};

    uint4 g0a0, g0a1, g0b0, g0b1, g0b2, g0b3;
    uint4 g1a0, g1a1, g1b0, g1b1, g1b2, g1b3;

#define LOADG(G, c) do {                                                  \
    G##a0 = *(const uint4*)(asrc + (size_t)(c) * 64);                     \
    G##a1 = *(const uint4*)(asrc + (size_t)(c) * 64 + 32);                \
    G##b0 = *(const uint4*)(bsrc + (size_t)(c) * 64);                     \
    G##b1 = *(const uint4*)(bsrc + (size_t)(c) * 64 + 8);                 \
    G##b2 = *(const uint4*)(bsrc + (size_t)(c) * 64 + 16);                \
    G##b3 = *(const uint4*)(bsrc + (size_t)(c) * 64 + 24); } while (0)

#define WRITEB(P, G) do {                                                 \
    *(uint4*)(&As[P][pa][arow][awd0])  = G##a0;                           \
    *(uint4*)(&As[P][pa][arow][awd1])  = G##a1;                           \
    *(uint4*)(&Bs[P][pa][brow][bwd[0]]) = G##b0;                          \
    *(uint4*)(&Bs[P][pa][brow][bwd[1]]) = G##b1;                          \
    *(uint4*)(&Bs[P][pa][brow][bwd[2]]) = G##b2;                          \
    *(uint4*)(&Bs[P][pa][brow][bwd[3]]) = G##b3; } while (0)

#define COMPUTE(P) do {                                                   \
    _Pragma("unroll")                                                     \
    for (int ks = 0; ks < 2; ++ks) {                                      \
        const int ra = wm * 16 + lr;                                      \
        const int koA = ((ks * 4 + lk) ^ (ra & 7)) * 8;                   \
        bfrag ah = *(const bfrag*)&As[P][0][ra][koA];                     \
        bfrag al = *(const bfrag*)&As[P][1][ra][koA];                     \
        _Pragma("unroll")                                                 \
        for (int ni = 0; ni < 2; ++ni) {                                  \
            const int rb = wn * 32 + ni * 16 + lr;                        \
            const int koB = ((ks * 4 + lk) ^ (rb & 7)) * 8;               \
            bfrag bh = *(const bfrag*)&Bs[P][0][rb][koB];                 \
            bfrag bl = *(const bfrag*)&Bs[P][1][rb][koB];                 \
            acc[ni] = __builtin_amdgcn_mfma_f32_16x16x32_bf16(            \
                ah, bh, acc[ni], 0, 0, 0);                                \
            acc[ni] = __builtin_amdgcn_mfma_f32_16x16x32_bf16(            \
                ah, bl, acc[ni], 0, 0, 0);                                \
            acc[ni] = __builtin_amdgcn_mfma_f32_16x16x32_bf16(            \
                al, bh, acc[ni], 0, 0, 0);                                \
        }                                                                 \
    } } while (0)

    LOADG(g0, 0);
    WRITEB(0, g0);
    LOADG(g1, 1);
    __syncthreads();

#pragma unroll
    for (int c = 0; c < 8; ++c) {
        if (c + 1 < 8) {
            if ((c + 1) & 1) WRITEB(1, g1); else WRITEB(0, g0);
        }
        if (c + 2 < 8) {
            if (c & 1) LOADG(g1, c + 2); else LOADG(g0, c + 2);
        }
        COMPUTE(c & 1);
        __syncthreads();
    }
#undef LOADG
#undef WRITEB
#undef COMPUTE

    const float SC = 2.885390081777926815f;   // 2*log2(e)
#pragma unroll
    for (int ni = 0; ni < 2; ++ni) {
        const int col = nt * 64 + wn * 32 + ni * 16 + lr;   // original h
        const int colp = (col & ~7) | (((col & 3) << 1) | ((col >> 2) & 1));
        const float bc = bias[col];
#pragma unroll
        for (int rr = 0; rr < 4; ++rr) {
            const int row = orow0 + wm * 16 + lk * 4 + rr;
            out[(size_t)row * 256 + colp] =
                __builtin_amdgcn_exp2f(SC * (acc[ni][rr] + bc));
        }
    }
}

// ---------------------------------------------------------------------------
// logits: sr[b][q][m] = sum_h wl[h]/(Eq*Ek+1), packed-f32.
// R8 post-mortem: cycle model shows LDS-port (10 b128 ops/chunk/wave ~ 120cyc)
// is ~2x the packed-VALU cost — R7/R8 restructures never changed that ratio
// (hence neutral). Fix: 4 q-rows per thread (was 2) — the 8 k4 ds_reads per
// chunk amortize over 4 q -> LDS-port demand HALVES (~13 -> ~6.5us), VALU
// unchanged (~6us), now balanced+overlapped. Blocks: 8b x 16mt x 8qt = 1024
// (4/CU). Per-(q,m) accumulation order identical -> bit-identical results.
// ---------------------------------------------------------------------------
__device__ __forceinline__ f2 qterm8(const float4 k4a, const float4 k4b,
                                     const float4 q4a, const float4 q4b,
                                     const float4 w4a, const float4 w4b,
                                     f2 acc) {
    f2 kp0 = {k4a.x, k4a.y}, kp1 = {k4a.z, k4a.w};
    f2 kp2 = {k4b.x, k4b.y}, kp3 = {k4b.z, k4b.w};
    f2 qp0 = {q4a.x, q4a.y}, qp1 = {q4a.z, q4a.w};
    f2 qp2 = {q4b.x, q4b.y}, qp3 = {q4b.z, q4b.w};
    f2 wp0 = {w4a.x, w4a.y}, wp1 = {w4a.z, w4a.w};
    f2 wp2 = {w4b.x, w4b.y}, wp3 = {w4b.z, w4b.w};
    const f2 one2 = {1.0f, 1.0f};
    f2 pp0 = __builtin_elementwise_fma(kp0, qp0, one2);
    f2 pp1 = __builtin_elementwise_fma(kp1, qp1, one2);
    f2 pp2 = __builtin_elementwise_fma(kp2, qp2, one2);
    f2 pp3 = __builtin_elementwise_fma(kp3, qp3, one2);
    f2 p01 = pp0 * pp1, p23 = pp2 * pp3;
    f2 n01 = __builtin_elementwise_fma(wp1, pp0, wp0 * pp1);
    f2 n23 = __builtin_elementwise_fma(wp3, pp2, wp2 * pp3);
    f2 Nm  = __builtin_elementwise_fma(n23, p01, n01 * p23);
    f2 P   = p01 * p23;
    f2 r   = {__builtin_amdgcn_rcpf(P.x), __builtin_amdgcn_rcpf(P.y)};
    return __builtin_elementwise_fma(Nm, r, acc);
}

__global__ __launch_bounds__(256) void logits_kernel(
    const float* __restrict__ Eq, const float* __restrict__ Ek,
    const float* __restrict__ wlp, float* __restrict__ sr) {
    const int bid = blockIdx.x;
    const int b  = bid & 7;
    const int r2 = bid >> 3;
    const int mt = r2 & 15;     // m tile of 64
    const int qt = r2 >> 4;     // q 16-group (0..7)
    const int tid = threadIdx.x;
    const int m  = tid & 63;
    const int qh = __builtin_amdgcn_readfirstlane(tid >> 6);  // 0..3, wave-uniform

    __shared__ float kq[2][8][64][4];   // [buf][h'-quad of 32h-chunk][m][4] = 16 KB

    const float* q0 = Eq + ((size_t)(b * QL_ + qt * 16 + qh * 4)) * H_;  // 4 q rows
    const float* kpb = Ek + ((size_t)(b * ML_ + mt * 64)) * H_;

    // staging: lane covers row srow, h-range [8*sq, 8*sq+8) of each 32h chunk
    const int srow = tid & 63;
    const int sq   = tid >> 6;           // 0..3
    const float* kst = kpb + (size_t)srow * H_ + 8 * sq;

    // prologue: chunk0 -> buf0; prefetch chunk1 into regs
    float4 a0 = *(const float4*)(kst);
    float4 a1 = *(const float4*)(kst + 4);
    *(float4*)(&kq[0][2 * sq + 0][srow][0]) = a0;
    *(float4*)(&kq[0][2 * sq + 1][srow][0]) = a1;
    a0 = *(const float4*)(kst + 32);
    a1 = *(const float4*)(kst + 36);
    __syncthreads();

    f2 accp[4];
#pragma unroll
    for (int j = 0; j < 4; ++j) accp[j] = (f2){0.f, 0.f};

    for (int c = 0; c < 8; ++c) {
        const int cb = c & 1;
        if (c < 7) {                        // stage chunk c+1 into other buf
            *(float4*)(&kq[cb ^ 1][2 * sq + 0][srow][0]) = a0;
            *(float4*)(&kq[cb ^ 1][2 * sq + 1][srow][0]) = a1;
            if (c < 6) {                    // prefetch chunk c+2 (2 ahead)
                a0 = *(const float4*)(kst + (c + 2) * 32);
                a1 = *(const float4*)(kst + (c + 2) * 32 + 4);
            }
        }
        const int h0 = c * 32;
#pragma unroll
        for (int pg = 0; pg < 4; ++pg) {
            float4 k4a = *(const float4*)(&kq[cb][2 * pg + 0][m][0]);
            float4 k4b = *(const float4*)(&kq[cb][2 * pg + 1][m][0]);
            float4 w4a = *(const float4*)(wlp + h0 + pg * 8);
            float4 w4b = *(const float4*)(wlp + h0 + pg * 8 + 4);
#pragma unroll
            for (int j = 0; j < 4; ++j) {
                float4 q4a = *(const float4*)(q0 + (size_t)j * H_ + h0 + pg * 8);
                float4 q4b = *(const float4*)(q0 + (size_t)j * H_ + h0 + pg * 8 + 4);
                accp[j] = qterm8(k4a, k4b, q4a, q4b, w4a, w4b, accp[j]);
            }
        }
        __syncthreads();
    }
    const size_t ro = ((size_t)(b * QL_ + qt * 16 + qh * 4)) * ML_ + mt * 64 + m;
#pragma unroll
    for (int j = 0; j < 4; ++j)
        sr[ro + (size_t)j * ML_] = accp[j].x + accp[j].y;
}

// ---------------------------------------------------------------------------
// In-place masked softmax + bf16 hi/lo split of weights for the MFMA
// attn_out (A-operand). logits_eff = -2*sr (shift-invariant). (R7 version)
// ---------------------------------------------------------------------------
__global__ __launch_bounds__(256) void softmax_kernel(
    float* __restrict__ wrow_io, const unsigned char* __restrict__ mv,
    unsigned short* __restrict__ Wbhi, unsigned short* __restrict__ Wblo) {
    const int row = blockIdx.x;
    const int b = row >> 7;
    const int tid = threadIdx.x;
    float* srow = wrow_io + (size_t)row * ML_;
    const unsigned char* mrow = mv + b * ML_;
    __shared__ float red[4];

    float4 s4 = *(const float4*)(srow + tid * 4);
    uchar4 m4 = *(const uchar4*)(mrow + tid * 4);
    float l[4];
    l[0] = m4.x ? -1e18f : -2.0f * s4.x;
    l[1] = m4.y ? -1e18f : -2.0f * s4.y;
    l[2] = m4.z ? -1e18f : -2.0f * s4.z;
    l[3] = m4.w ? -1e18f : -2.0f * s4.w;

    float mx = fmaxf(fmaxf(l[0], l[1]), fmaxf(l[2], l[3]));
#pragma unroll
    for (int off = 32; off >= 1; off >>= 1)
        mx = fmaxf(mx, __shfl_xor(mx, off));
    if ((tid & 63) == 0) red[tid >> 6] = mx;
    __syncthreads();
    mx = fmaxf(fmaxf(red[0], red[1]), fmaxf(red[2], red[3]));
    __syncthreads();

    const float L2E = 1.44269504088896340736f;
    float e[4], s = 0.f;
#pragma unroll
    for (int i = 0; i < 4; ++i) {
        e[i] = __builtin_amdgcn_exp2f((l[i] - mx) * L2E);
        s += e[i];
    }
#pragma unroll
    for (int off = 32; off >= 1; off >>= 1)
        s += __shfl_xor(s, off);
    if ((tid & 63) == 0) red[tid >> 6] = s;
    __syncthreads();
    s = (red[0] + red[1]) + (red[2] + red[3]);
    float inv = __builtin_amdgcn_rcpf(s);
    float4 o = make_float4(e[0] * inv, e[1] * inv, e[2] * inv, e[3] * inv);
    *(float4*)(srow + tid * 4) = o;

    unsigned h01, h23, l01, l23;
    split4(o, h01, h23, l01, l23);
    *(uint2*)(Wbhi + (size_t)row * ML_ + tid * 4) = make_uint2(h01, h23);
    *(uint2*)(Wblo + (size_t)row * ML_ + tid * 4) = make_uint2(l01, l23);
}

// ---------------------------------------------------------------------------
// attns[b] = weights[b] (128x1024) @ memory[b] (1024x512), bf16x3 MFMA.
// (unchanged — validated-fast schedule from R6)
// ---------------------------------------------------------------------------
__global__ __launch_bounds__(256) void attn_out_kernel(
    const unsigned short* __restrict__ Wbhi, const unsigned short* __restrict__ Wblo,
    const unsigned short* __restrict__ MThi, const unsigned short* __restrict__ MTlo,
    float* __restrict__ out) {
    const int bid = blockIdx.x;
    const int b  = bid & 7;
    const int r  = bid >> 3;          // 0..63
    const int mt = r & 7;             // m tile of 16
    const int nt = r >> 3;            // n tile of 64
    const int t = threadIdx.x;
    const int w  = t >> 6;
    const int l  = t & 63;
    const int lr = l & 15, lk = l >> 4;

    __shared__ unsigned short As[2][16][2][64];   // [buf][row][plane][k]
    __shared__ unsigned short Bs[2][64][2][64];

    const int pa  = t >> 7;
    const int ar  = (t >> 3) & 15;
    const int acq = t & 7;
    const unsigned short* asrc = (pa ? Wblo : Wbhi)
        + ((size_t)(b * QL_ + mt * 16 + ar)) * ML_ + acq * 8;
    const int aws = (acq ^ (ar & 7)) * 8;

    const int pb  = t >> 7;
    const int br  = (t & 127) >> 1;
    const int bq0 = (t & 1) * 4;
    const unsigned short* bsrc = (pb ? MTlo : MThi)
        + ((size_t)(b * KS_ + nt * 64 + br)) * ML_ + bq0 * 8;
    int bws[4];
#pragma unroll
    for (int i2 = 0; i2 < 4; ++i2) bws[i2] = ((bq0 + i2) ^ (br & 7)) * 8;

    f4acc acc = (f4acc){0.f, 0.f, 0.f, 0.f};

    uint4 g0a, g0b0, g0b1, g0b2, g0b3;
    uint4 g1a, g1b0, g1b1, g1b2, g1b3;

#define LOADG(G, c) do {                                                  \
    G##a  = *(const uint4*)(asrc + (size_t)(c) * 64);                     \
    G##b0 = *(const uint4*)(bsrc + (size_t)(c) * 64);                     \
    G##b1 = *(const uint4*)(bsrc + (size_t)(c) * 64 + 8);                 \
    G##b2 = *(const uint4*)(bsrc + (size_t)(c) * 64 + 16);                \
    G##b3 = *(const uint4*)(bsrc + (size_t)(c) * 64 + 24); } while (0)

#define WRITEB(P, G) do {                                                 \
    *(uint4*)(&As[P][ar][pa][aws])    = G##a;                             \
    *(uint4*)(&Bs[P][br][pb][bws[0]]) = G##b0;                            \
    *(uint4*)(&Bs[P][br][pb][bws[1]]) = G##b1;                            \
    *(uint4*)(&Bs[P][br][pb][bws[2]]) = G##b2;                            \
    *(uint4*)(&Bs[P][br][pb][bws[3]]) = G##b3; } while (0)

#define COMPUTE(P) do {                                                   \
    _Pragma("unroll")                                                     \
    for (int ks = 0; ks < 2; ++ks) {                                      \
        const int k8 = (ks * 4 + lk) ^ (lr & 7);                          \
        bfrag ah = *(const bfrag*)&As[P][lr][0][k8 * 8];                  \
        bfrag al = *(const bfrag*)&As[P][lr][1][k8 * 8];                  \
        bfrag bh = *(const bfrag*)&Bs[P][w * 16 + lr][0][k8 * 8];         \
        bfrag bl = *(const bfrag*)&Bs[P][w * 16 + lr][1][k8 * 8];         \
        acc = __builtin_amdgcn_mfma_f32_16x16x32_bf16(ah, bh, acc, 0,0,0);\
        acc = __builtin_amdgcn_mfma_f32_16x16x32_bf16(ah, bl, acc, 0,0,0);\
        acc = __builtin_amdgcn_mfma_f32_16x16x32_bf16(al, bh, acc, 0,0,0);\
    } } while (0)

    LOADG(g0, 0);
    WRITEB(0, g0);
    LOADG(g1, 1);
    __syncthreads();

#pragma unroll
    for (int c = 0; c < 16; ++c) {
        if (c + 1 < 16) {
            if ((c + 1) & 1) WRITEB(1, g1); else WRITEB(0, g0);
        }
        if (c + 2 < 16) {
            if (c & 1) LOADG(g1, c + 2); else LOADG(g0, c + 2);
        }
        COMPUTE(c & 1);
        __syncthreads();
    }
#undef LOADG
#undef WRITEB
#undef COMPUTE

    const int col = nt * 64 + w * 16 + lr;
#pragma unroll
    for (int rr = 0; rr < 4; ++rr) {
        const int row = mt * 16 + lk * 4 + rr;
        out[((size_t)(b * QL_ + row)) * KS_ + col] = acc[rr];
    }
}

extern "C" void kernel_launch(void* const* d_in, const int* in_sizes, int n_in,
                              void* d_out, int out_size, void* d_ws, size_t ws_size,
                              hipStream_t stream) {
    const float* query  = (const float*)d_in[0];
    const float* memory = (const float*)d_in[1];
    const unsigned char* mask = (const unsigned char*)d_in[2];
    const float* Wq = (const float*)d_in[3];
    const float* bq = (const float*)d_in[4];
    const float* Wk = (const float*)d_in[5];
    const float* bk = (const float*)d_in[6];
    const float* wl = (const float*)d_in[7];
    // d_in[8] (bl) cancels under softmax shift-invariance; not read.

    float* ws = (float*)d_ws;
    float* Eq = ws + QP_OFF;
    float* Ek = ws + KP_OFF;
    unsigned char* mcan = (unsigned char*)(ws + MASK_OFF);
    unsigned short* Whi  = (unsigned short*)(ws + WH_OFF);
    unsigned short* Wlo  = (unsigned short*)(ws + WL_OFF);
    unsigned short* MThi = (unsigned short*)(ws + MT_H_OFF);
    unsigned short* MTlo = (unsigned short*)(ws + MT_L_OFF);
    unsigned short* Wbhi = (unsigned short*)(ws + WB_H_OFF);
    unsigned short* Wblo = (unsigned short*)(ws + WB_L_OFF);
    unsigned short* Xhi  = (unsigned short*)(ws + XH_OFF);
    unsigned short* Xlo  = (unsigned short*)(ws + XL_OFF);
    float* wlp = ws + WLP_OFF;

    float* attns = (float*)d_out;                      // [B][QL][KS]
    float* wout  = (float*)d_out + B_ * QL_ * KS_;     // [B][QL][ML] (also sr scratch)

    prep_kernel<<<dim3(2241), dim3(256), 0, stream>>>(query, memory, Wq, Wk, wl,
                                                      Whi, Wlo, Xhi, Xlo,
                                                      MThi, MTlo, mask, mcan, wlp);
    proj_kernel<<<dim3(1152), dim3(256), 0, stream>>>(Xhi, Xlo, Whi, Wlo,
                                                      bq, bk, Eq, Ek);
    logits_kernel<<<dim3(1024), dim3(256), 0, stream>>>(Eq, Ek, wlp, wout);
    softmax_kernel<<<dim3(B_ * QL_), dim3(256), 0, stream>>>(wout, mcan, Wbhi, Wblo);
    attn_out_kernel<<<dim3(512), dim3(256), 0, stream>>>(Wbhi, Wblo, MThi, MTlo, attns);
}

// Round 10
// 156.575 us; speedup vs baseline: 1.0286x; 1.0286x over previous
//
#include <hip/hip_runtime.h>

#define B_  8
#define QL_ 128
#define ML_ 1024
#define KS_ 512
#define H_  256

// ws layout (floats):
//   Eq (h-PERMUTED) [B][QL][H]            @ 0        (262144)
//   Ek (h-PERMUTED) [B][ML][H]            @ 262144   (2097152)
//   mask canonical uint8 [B*ML]           @ 2359296  (2048 float slots)
//   Whi bf16 [512][512]                   @ 2361344  (131072)
//   Wlo bf16 [512][512]                   @ 2492416  (131072)
//   MThi bf16 [8][512][1024] (memory^T)   @ 2623488  (2097152)
//   MTlo bf16 [8][512][1024]              @ 4720640  (2097152)
//   Wbhi bf16 [8][128][1024] (weights)    @ 6817792  (524288)
//   Wblo bf16 [8][128][1024]              @ 7342080  (524288)
//   Xhi bf16 [9216][512] (query|memory)   @ 7866368  (2359296)
//   Xlo bf16 [9216][512]                  @ 10225664 (2359296)
//   wlp (h-PERMUTED wl) [256]             @ 12584960 (256)
// h-permutation (within each 8-group): orig o -> ((o&3)<<1)|(o>>2): pairs are
// (h_j, h_{j+4}) -> packed-f32 (v_pk_fma_f32) processing of 2 rcp-quads.
#define QP_OFF 0
#define KP_OFF 262144
#define MASK_OFF 2359296
#define WH_OFF 2361344
#define WL_OFF 2492416
#define MT_H_OFF 2623488
#define MT_L_OFF 4720640
#define WB_H_OFF 6817792
#define WB_L_OFF 7342080
#define XH_OFF 7866368
#define XL_OFF 10225664
#define WLP_OFF 12584960

typedef __attribute__((ext_vector_type(8))) short bfrag;   // 8 bf16 (4 VGPR)
typedef __attribute__((ext_vector_type(4))) float f4acc;   // MFMA acc
typedef __attribute__((ext_vector_type(2))) float f2;      // packed f32 pair

// fp32 -> (hi,lo) bf16 split. hi = truncation (residual <= 2^-8|x|, captured
// exactly by fp32 subtract); lo = RNE of residual (final err <= 2^-17|x|).
__device__ __forceinline__ void split1(float v, unsigned& h, unsigned& lo) {
    unsigned u  = __float_as_uint(v);
    unsigned hb = u & 0xFFFF0000u;
    float    lf = v - __uint_as_float(hb);           // exact
    unsigned ul = __float_as_uint(lf);
    unsigned lr = ul + 0x7FFFu + ((ul >> 16) & 1u);  // RNE
    h  = u >> 16;
    lo = lr >> 16;
}

__device__ __forceinline__ void split4(const float4& a, unsigned& h01, unsigned& h23,
                                       unsigned& l01, unsigned& l23) {
    unsigned h[4], l[4];
    split1(a.x, h[0], l[0]); split1(a.y, h[1], l[1]);
    split1(a.z, h[2], l[2]); split1(a.w, h[3], l[3]);
    h01 = h[0] | (h[1] << 16); h23 = h[2] | (h[3] << 16);
    l01 = l[0] | (l[1] << 16); l23 = l[2] | (l[3] << 16);
}

// ---------------------------------------------------------------------------
// Prep kernel, grid 1217 x 256. The memory-transpose-split (MT) has been
// MOVED to the logits launch: MT is only consumed by attn_out (2 launches
// later), and logits is compute-bound — MT's ~50 MB of HBM traffic hides
// under logits' VALU time instead of serializing here (R8 paired MT with
// the BW-bound softmax: neutral; compute-bound partner is the right one).
//   bid 0..63     : W split (Wq rows 0..255, Wk rows 256..511 of Whi/Wlo)
//   bid 64..191   : query  -> Xhi/Xlo rows 0..1023
//   bid 192..1215 : memory -> Xhi/Xlo rows 1024..9215
//   bid 1216      : mask canonicalizer + permuted-wl copy
// ---------------------------------------------------------------------------
__global__ __launch_bounds__(256) void prep_kernel(
    const float* __restrict__ query, const float* __restrict__ memory,
    const float* __restrict__ Wq, const float* __restrict__ Wk,
    const float* __restrict__ wl,
    unsigned short* __restrict__ Whi, unsigned short* __restrict__ Wlo,
    unsigned short* __restrict__ Xhi, unsigned short* __restrict__ Xlo,
    const unsigned char* __restrict__ mraw, unsigned char* __restrict__ mout,
    float* __restrict__ wlp) {
    const int bid = blockIdx.x;
    const int t = threadIdx.x;

    if (bid == 1216) {   // ---- mask canonicalizer + wl permute ----
        wlp[(t & ~7) | (((t & 3) << 1) | ((t >> 2) & 1))] = wl[t];
        __shared__ int s_not01, s_not0f;
        const unsigned int* w = (const unsigned int*)mraw;
        if (t == 0) { s_not01 = 0; s_not0f = 0; }
        __syncthreads();
        int not01 = 0, not0f = 0;
        for (int i = t; i < 2048; i += 256) {
            unsigned int v = w[i];
            if (v != 0u && v != 1u) not01 = 1;
            if (v != 0u && v != 0x3F800000u) not0f = 1;
        }
        if (not01) atomicOr(&s_not01, 1);
        if (not0f) atomicOr(&s_not0f, 1);
        __syncthreads();
        int wordTyped = (!s_not01) || (!s_not0f);
        for (int i = t; i < B_ * ML_; i += 256) {
            unsigned char mv;
            if (wordTyped) mv = (w[i] != 0u) ? 1 : 0;
            else           mv = mraw[i] ? 1 : 0;
            mout[i] = mv;
        }
        return;
    }

    // ---- linear hi/lo splits: W planes and X planes ----
    const float* src; unsigned short *dh, *dl; size_t soff, doff;
    if (bid < 64) {
        src = (bid < 32) ? Wq : Wk;
        soff = (size_t)(bid & 31) * 4096;
        doff = ((bid < 32) ? 0 : 131072) + soff;
        dh = Whi; dl = Wlo;
    } else if (bid < 192) {
        src = query;  soff = (size_t)(bid - 64) * 4096;  doff = soff;
        dh = Xhi; dl = Xlo;
    } else {
        src = memory; soff = (size_t)(bid - 192) * 4096; doff = 524288 + soff;
        dh = Xhi; dl = Xlo;
    }
    soff += (size_t)t * 16; doff += (size_t)t * 16;

    unsigned hw[8], lw[8];
#pragma unroll
    for (int i = 0; i < 4; ++i) {
        float4 v = *(const float4*)(src + soff + i * 4);
        split4(v, hw[i * 2], hw[i * 2 + 1], lw[i * 2], lw[i * 2 + 1]);
    }
    *(uint4*)(dh + doff)     = make_uint4(hw[0], hw[1], hw[2], hw[3]);
    *(uint4*)(dh + doff + 8) = make_uint4(hw[4], hw[5], hw[6], hw[7]);
    *(uint4*)(dl + doff)     = make_uint4(lw[0], lw[1], lw[2], lw[3]);
    *(uint4*)(dl + doff + 8) = make_uint4(lw[4], lw[5], lw[6], lw[7]);
}

// ---------------------------------------------------------------------------
// Projection via bf16x3-split MFMA — UNCHANGED (validated in R7's −9 us win).
// attn_out-style schedule: pre-split operands, BK=64, 1 barrier/chunk,
// reg-prefetch 2 chunks ahead, XOR-swizzled LDS. Stores h-PERMUTED Eq/Ek.
// ---------------------------------------------------------------------------
__global__ __launch_bounds__(256) void proj_kernel(
    const unsigned short* __restrict__ Xhi, const unsigned short* __restrict__ Xlo,
    const unsigned short* __restrict__ Whi, const unsigned short* __restrict__ Wlo,
    const float* __restrict__ bq, const float* __restrict__ bk,
    float* __restrict__ Eq, float* __restrict__ Ek) {
    const int bid = blockIdx.x;
    const int t = threadIdx.x;
    const int wk = (bid & 7) * 144 + (bid >> 3);   // XCD-chunked (1152 = 8*144)
    const int nt = wk & 3;
    const int mt = wk >> 2;          // 0..287

    const bool isQ = (mt < 32);
    const int arow0 = mt * 32;
    const int orow0 = isQ ? arow0 : arow0 - 1024;
    const float* bias = isQ ? bq : bk;
    float* out = isQ ? Eq : Ek;
    const int wrb = (isQ ? 0 : 256) + nt * 64;

    const int w  = t >> 6;
    const int wm = w >> 1, wn = w & 1;   // wave = 16m x 32n
    const int l  = t & 63;
    const int lr = l & 15, lk = l >> 4;

    __shared__ unsigned short As[2][2][32][64];   // [buf][plane][row][k]
    __shared__ unsigned short Bs[2][2][64][64];

    const int pa   = t >> 7;
    const int slot = t & 127;
    const int arow = slot >> 2, ao = slot & 3;
    const int brow = slot >> 1, bo0 = (slot & 1) * 4;
    const unsigned short* asrc = (pa ? Xlo : Xhi) + (size_t)(arow0 + arow) * 512 + ao * 8;
    const unsigned short* bsrc = (pa ? Wlo : Whi) + (size_t)(wrb + brow) * 512 + bo0 * 8;
    const int awd0 = (ao ^ (arow & 7)) * 8;
    const int awd1 = ((ao + 4) ^ (arow & 7)) * 8;
    int bwd[4];
#pragma unroll
    for (int i = 0; i < 4; ++i) bwd[i] = ((bo0 + i) ^ (brow & 7)) * 8;

    f4acc acc[2];
    acc[0] = (f4acc){0.f, 0.f, 0.f, 0.f};
    acc[1] = (f4acc){0.f, 0.f, 0.f, 0.f};

    uint4 g0a0, g0a1, g0b0, g0b1, g0b2, g0b3;
    uint4 g1a0, g1a1, g1b0, g1b1, g1b2, g1b3;

#define LOADG(G, c) do {                                                  \
    G##a0 = *(const uint4*)(asrc + (size_t)(c) * 64);                     \
    G##a1 = *(const uint4*)(asrc + (size_t)(c) * 64 + 32);                \
    G##b0 = *(const uint4*)(bsrc + (size_t)(c) * 64);                     \
    G##b1 = *(const uint4*)(bsrc + (size_t)(c) * 64 + 8);                 \
    G##b2 = *(const uint4*)(bsrc + (size_t)(c) * 64 + 16);                \
    G##b3 = *(const uint4*)(bsrc + (size_t)(c) * 64 + 24); } while (0)

#define WRITEB(P, G) do {                                                 \
    *(uint4*)(&As[P][pa][arow][awd0])  = G##a0;                           \
    *(uint4*)(&As[P][pa][arow][awd1])  = G##a1;                           \
    *(uint4*)(&Bs[P][pa][brow][bwd[0]]) = G##b0;                          \
    *(uint4*)(&Bs[P][pa][brow][bwd[1]]) = G##b1;                          \
    *(uint4*)(&Bs[P][pa][brow][bwd[2]]) = G##b2;                          \
    *(uint4*)(&Bs[P][pa][brow][bwd[3]]) = G##b3; } while (0)

#define COMPUTE(P) do {                                                   \
    _Pragma("unroll")                                                     \
    for (int ks = 0; ks < 2; ++ks) {                                      \
        const int ra = wm * 16 + lr;                                      \
        const int koA = ((ks * 4 + lk) ^ (ra & 7)) * 8;                   \
        bfrag ah = *(const bfrag*)&As[P][0][ra][koA];                     \
        bfrag al = *(const bfrag*)&As[P][1][ra][koA];                     \
        _Pragma("unroll")                                                 \
        for (int ni = 0; ni < 2; ++ni) {                                  \
            const int rb = wn * 32 + ni * 16 + lr;                        \
            const int koB = ((ks * 4 + lk) ^ (rb & 7)) * 8;               \
            bfrag bh = *(const bfrag*)&Bs[P][0][rb][koB];                 \
            bfrag bl = *(const bfrag*)&Bs[P][1][rb][koB];                 \
            acc[ni] = __builtin_amdgcn_mfma_f32_16x16x32_bf16(            \
                ah, bh, acc[ni], 0, 0, 0);                                \
            acc[ni] = __builtin_amdgcn_mfma_f32_16x16x32_bf16(            \
                ah, bl, acc[ni], 0, 0, 0);                                \
            acc[ni] = __builtin_amdgcn_mfma_f32_16x16x32_bf16(            \
                al, bh, acc[ni], 0, 0, 0);                                \
        }                                                                 \
    } } while (0)

    LOADG(g0, 0);
    WRITEB(0, g0);
    LOADG(g1, 1);
    __syncthreads();

#pragma unroll
    for (int c = 0; c < 8; ++c) {
        if (c + 1 < 8) {
            if ((c + 1) & 1) WRITEB(1, g1); else WRITEB(0, g0);
        }
        if (c + 2 < 8) {
            if (c & 1) LOADG(g1, c + 2); else LOADG(g0, c + 2);
        }
        COMPUTE(c & 1);
        __syncthreads();
    }
#undef LOADG
#undef WRITEB
#undef COMPUTE

    const float SC = 2.885390081777926815f;   // 2*log2(e)
#pragma unroll
    for (int ni = 0; ni < 2; ++ni) {
        const int col = nt * 64 + wn * 32 + ni * 16 + lr;   // original h
        const int colp = (col & ~7) | (((col & 3) << 1) | ((col >> 2) & 1));
        const float bc = bias[col];
#pragma unroll
        for (int rr = 0; rr < 4; ++rr) {
            const int row = orow0 + wm * 16 + lk * 4 + rr;
            out[(size_t)row * 256 + colp] =
                __builtin_amdgcn_exp2f(SC * (acc[ni][rr] + bc));
        }
    }
}

// ---------------------------------------------------------------------------
// logits launch, grid 2048:
//   bid 0..1023   : logits (R9 math — 4 q-rows/thread, bit-identical)
//   bid 1024..2047: memory transpose-split -> MThi/MTlo (moved from prep:
//                   BW-bound MT overlaps compute-bound logits blocks)
// Shared LDS is unioned (17.4 KB) so logits occupancy stays thread-capped.
// ---------------------------------------------------------------------------
__device__ __forceinline__ f2 qterm8(const float4 k4a, const float4 k4b,
                                     const float4 q4a, const float4 q4b,
                                     const float4 w4a, const float4 w4b,
                                     f2 acc) {
    f2 kp0 = {k4a.x, k4a.y}, kp1 = {k4a.z, k4a.w};
    f2 kp2 = {k4b.x, k4b.y}, kp3 = {k4b.z, k4b.w};
    f2 qp0 = {q4a.x, q4a.y}, qp1 = {q4a.z, q4a.w};
    f2 qp2 = {q4b.x, q4b.y}, qp3 = {q4b.z, q4b.w};
    f2 wp0 = {w4a.x, w4a.y}, wp1 = {w4a.z, w4a.w};
    f2 wp2 = {w4b.x, w4b.y}, wp3 = {w4b.z, w4b.w};
    const f2 one2 = {1.0f, 1.0f};
    f2 pp0 = __builtin_elementwise_fma(kp0, qp0, one2);
    f2 pp1 = __builtin_elementwise_fma(kp1, qp1, one2);
    f2 pp2 = __builtin_elementwise_fma(kp2, qp2, one2);
    f2 pp3 = __builtin_elementwise_fma(kp3, qp3, one2);
    f2 p01 = pp0 * pp1, p23 = pp2 * pp3;
    f2 n01 = __builtin_elementwise_fma(wp1, pp0, wp0 * pp1);
    f2 n23 = __builtin_elementwise_fma(wp3, pp2, wp2 * pp3);
    f2 Nm  = __builtin_elementwise_fma(n23, p01, n01 * p23);
    f2 P   = p01 * p23;
    f2 r   = {__builtin_amdgcn_rcpf(P.x), __builtin_amdgcn_rcpf(P.y)};
    return __builtin_elementwise_fma(Nm, r, acc);
}

__global__ __launch_bounds__(256) void logits_kernel(
    const float* __restrict__ Eq, const float* __restrict__ Ek,
    const float* __restrict__ wlp, float* __restrict__ sr,
    const float* __restrict__ memory,
    unsigned short* __restrict__ MThi, unsigned short* __restrict__ MTlo) {
    const int tid = threadIdx.x;
    __shared__ __align__(16) unsigned char smem[17408];   // union: kq | T

    if (blockIdx.x >= 1024) {   // ---- memory transpose-split (64x64 tile) ----
        float (*T)[68] = (float(*)[68])smem;              // [64][68]
        const int idx = blockIdx.x - 1024;   // 0..1023
        const int b  = idx >> 7;
        const int r  = idx & 127;
        const int mt = r >> 3;
        const int st = r & 7;

        const int i  = tid >> 2, jb = (tid & 3) << 4;
        const float* mp = memory + ((size_t)(b * ML_ + mt * 64 + i)) * KS_ + st * 64 + jb;
#pragma unroll
        for (int q = 0; q < 4; ++q)
            *(float4*)(&T[i][jb + q * 4]) = *(const float4*)(mp + q * 4);
        __syncthreads();

        const int s = tid >> 2, mb = (tid & 3) << 4;
        unsigned hh[16], ll[16];
#pragma unroll
        for (int e = 0; e < 16; ++e) split1(T[mb + e][s], hh[e], ll[e]);
        unsigned hp[8], lp[8];
#pragma unroll
        for (int e = 0; e < 8; ++e) {
            hp[e] = hh[2 * e] | (hh[2 * e + 1] << 16);
            lp[e] = ll[2 * e] | (ll[2 * e + 1] << 16);
        }
        const size_t doff = ((size_t)(b * KS_ + st * 64 + s)) * ML_ + mt * 64 + mb;
        *(uint4*)(MThi + doff)     = make_uint4(hp[0], hp[1], hp[2], hp[3]);
        *(uint4*)(MThi + doff + 8) = make_uint4(hp[4], hp[5], hp[6], hp[7]);
        *(uint4*)(MTlo + doff)     = make_uint4(lp[0], lp[1], lp[2], lp[3]);
        *(uint4*)(MTlo + doff + 8) = make_uint4(lp[4], lp[5], lp[6], lp[7]);
        return;
    }

    // ---- logits (R9 math, bit-identical) ----
    float (*kq)[8][64][4] = (float(*)[8][64][4])smem;     // [2][8][64][4]
    const int bid = blockIdx.x;
    const int b  = bid & 7;
    const int r2 = bid >> 3;
    const int mt = r2 & 15;     // m tile of 64
    const int qt = r2 >> 4;     // q 16-group (0..7)
    const int m  = tid & 63;
    const int qh = __builtin_amdgcn_readfirstlane(tid >> 6);  // 0..3, wave-uniform

    const float* q0 = Eq + ((size_t)(b * QL_ + qt * 16 + qh * 4)) * H_;  // 4 q rows
    const float* kpb = Ek + ((size_t)(b * ML_ + mt * 64)) * H_;

    const int srow = tid & 63;
    const int sq   = tid >> 6;           // 0..3
    const float* kst = kpb + (size_t)srow * H_ + 8 * sq;

    float4 a0 = *(const float4*)(kst);
    float4 a1 = *(const float4*)(kst + 4);
    *(float4*)(&kq[0][2 * sq + 0][srow][0]) = a0;
    *(float4*)(&kq[0][2 * sq + 1][srow][0]) = a1;
    a0 = *(const float4*)(kst + 32);
    a1 = *(const float4*)(kst + 36);
    __syncthreads();

    f2 accp[4];
#pragma unroll
    for (int j = 0; j < 4; ++j) accp[j] = (f2){0.f, 0.f};

    for (int c = 0; c < 8; ++c) {
        const int cb = c & 1;
        if (c < 7) {                        // stage chunk c+1 into other buf
            *(float4*)(&kq[cb ^ 1][2 * sq + 0][srow][0]) = a0;
            *(float4*)(&kq[cb ^ 1][2 * sq + 1][srow][0]) = a1;
            if (c < 6) {                    // prefetch chunk c+2 (2 ahead)
                a0 = *(const float4*)(kst + (c + 2) * 32);
                a1 = *(const float4*)(kst + (c + 2) * 32 + 4);
            }
        }
        const int h0 = c * 32;
#pragma unroll
        for (int pg = 0; pg < 4; ++pg) {
            float4 k4a = *(const float4*)(&kq[cb][2 * pg + 0][m][0]);
            float4 k4b = *(const float4*)(&kq[cb][2 * pg + 1][m][0]);
            float4 w4a = *(const float4*)(wlp + h0 + pg * 8);
            float4 w4b = *(const float4*)(wlp + h0 + pg * 8 + 4);
#pragma unroll
            for (int j = 0; j < 4; ++j) {
                float4 q4a = *(const float4*)(q0 + (size_t)j * H_ + h0 + pg * 8);
                float4 q4b = *(const float4*)(q0 + (size_t)j * H_ + h0 + pg * 8 + 4);
                accp[j] = qterm8(k4a, k4b, q4a, q4b, w4a, w4b, accp[j]);
            }
        }
        __syncthreads();
    }
    const size_t ro = ((size_t)(b * QL_ + qt * 16 + qh * 4)) * ML_ + mt * 64 + m;
#pragma unroll
    for (int j = 0; j < 4; ++j)
        sr[ro + (size_t)j * ML_] = accp[j].x + accp[j].y;
}

// ---------------------------------------------------------------------------
// In-place masked softmax + bf16 hi/lo split of weights for the MFMA
// attn_out (A-operand). logits_eff = -2*sr (shift-invariant).
// ---------------------------------------------------------------------------
__global__ __launch_bounds__(256) void softmax_kernel(
    float* __restrict__ wrow_io, const unsigned char* __restrict__ mv,
    unsigned short* __restrict__ Wbhi, unsigned short* __restrict__ Wblo) {
    const int row = blockIdx.x;
    const int b = row >> 7;
    const int tid = threadIdx.x;
    float* srow = wrow_io + (size_t)row * ML_;
    const unsigned char* mrow = mv + b * ML_;
    __shared__ float red[4];

    float4 s4 = *(const float4*)(srow + tid * 4);
    uchar4 m4 = *(const uchar4*)(mrow + tid * 4);
    float l[4];
    l[0] = m4.x ? -1e18f : -2.0f * s4.x;
    l[1] = m4.y ? -1e18f : -2.0f * s4.y;
    l[2] = m4.z ? -1e18f : -2.0f * s4.z;
    l[3] = m4.w ? -1e18f : -2.0f * s4.w;

    float mx = fmaxf(fmaxf(l[0], l[1]), fmaxf(l[2], l[3]));
#pragma unroll
    for (int off = 32; off >= 1; off >>= 1)
        mx = fmaxf(mx, __shfl_xor(mx, off));
    if ((tid & 63) == 0) red[tid >> 6] = mx;
    __syncthreads();
    mx = fmaxf(fmaxf(red[0], red[1]), fmaxf(red[2], red[3]));
    __syncthreads();

    const float L2E = 1.44269504088896340736f;
    float e[4], s = 0.f;
#pragma unroll
    for (int i = 0; i < 4; ++i) {
        e[i] = __builtin_amdgcn_exp2f((l[i] - mx) * L2E);
        s += e[i];
    }
#pragma unroll
    for (int off = 32; off >= 1; off >>= 1)
        s += __shfl_xor(s, off);
    if ((tid & 63) == 0) red[tid >> 6] = s;
    __syncthreads();
    s = (red[0] + red[1]) + (red[2] + red[3]);
    float inv = __builtin_amdgcn_rcpf(s);
    float4 o = make_float4(e[0] * inv, e[1] * inv, e[2] * inv, e[3] * inv);
    *(float4*)(srow + tid * 4) = o;

    unsigned h01, h23, l01, l23;
    split4(o, h01, h23, l01, l23);
    *(uint2*)(Wbhi + (size_t)row * ML_ + tid * 4) = make_uint2(h01, h23);
    *(uint2*)(Wblo + (size_t)row * ML_ + tid * 4) = make_uint2(l01, l23);
}

// ---------------------------------------------------------------------------
// attns[b] = weights[b] (128x1024) @ memory[b] (1024x512), bf16x3 MFMA.
// (unchanged — validated-fast schedule from R6)
// ---------------------------------------------------------------------------
__global__ __launch_bounds__(256) void attn_out_kernel(
    const unsigned short* __restrict__ Wbhi, const unsigned short* __restrict__ Wblo,
    const unsigned short* __restrict__ MThi, const unsigned short* __restrict__ MTlo,
    float* __restrict__ out) {
    const int bid = blockIdx.x;
    const int b  = bid & 7;
    const int r  = bid >> 3;          // 0..63
    const int mt = r & 7;             // m tile of 16
    const int nt = r >> 3;            // n tile of 64
    const int t = threadIdx.x;
    const int w  = t >> 6;
    const int l  = t & 63;
    const int lr = l & 15, lk = l >> 4;

    __shared__ unsigned short As[2][16][2][64];   // [buf][row][plane][k]
    __shared__ unsigned short Bs[2][64][2][64];

    const int pa  = t >> 7;
    const int ar  = (t >> 3) & 15;
    const int acq = t & 7;
    const unsigned short* asrc = (pa ? Wblo : Wbhi)
        + ((size_t)(b * QL_ + mt * 16 + ar)) * ML_ + acq * 8;
    const int aws = (acq ^ (ar & 7)) * 8;

    const int pb  = t >> 7;
    const int br  = (t & 127) >> 1;
    const int bq0 = (t & 1) * 4;
    const unsigned short* bsrc = (pb ? MTlo : MThi)
        + ((size_t)(b * KS_ + nt * 64 + br)) * ML_ + bq0 * 8;
    int bws[4];
#pragma unroll
    for (int i2 = 0; i2 < 4; ++i2) bws[i2] = ((bq0 + i2) ^ (br & 7)) * 8;

    f4acc acc = (f4acc){0.f, 0.f, 0.f, 0.f};

    uint4 g0a, g0b0, g0b1, g0b2, g0b3;
    uint4 g1a, g1b0, g1b1, g1b2, g1b3;

#define LOADG(G, c) do {                                                  \
    G##a  = *(const uint4*)(asrc + (size_t)(c) * 64);                     \
    G##b0 = *(const uint4*)(bsrc + (size_t)(c) * 64);                     \
    G##b1 = *(const uint4*)(bsrc + (size_t)(c) * 64 + 8);                 \
    G##b2 = *(const uint4*)(bsrc + (size_t)(c) * 64 + 16);                \
    G##b3 = *(const uint4*)(bsrc + (size_t)(c) * 64 + 24); } while (0)

#define WRITEB(P, G) do {                                                 \
    *(uint4*)(&As[P][ar][pa][aws])    = G##a;                             \
    *(uint4*)(&Bs[P][br][pb][bws[0]]) = G##b0;                            \
    *(uint4*)(&Bs[P][br][pb][bws[1]]) = G##b1;                            \
    *(uint4*)(&Bs[P][br][pb][bws[2]]) = G##b2;                            \
    *(uint4*)(&Bs[P][br][pb][bws[3]]) = G##b3; } while (0)

#define COMPUTE(P) do {                                                   \
    _Pragma("unroll")                                                     \
    for (int ks = 0; ks < 2; ++ks) {                                      \
        const int k8 = (ks * 4 + lk) ^ (lr & 7);                          \
        bfrag ah = *(const bfrag*)&As[P][lr][0][k8 * 8];                  \
        bfrag al = *(const bfrag*)&As[P][lr][1][k8 * 8];                  \
        bfrag bh = *(const bfrag*)&Bs[P][w * 16 + lr][0][k8 * 8];         \
        bfrag bl = *(const bfrag*)&Bs[P][w * 16 + lr][1][k8 * 8];         \
        acc = __builtin_amdgcn_mfma_f32_16x16x32_bf16(ah, bh, acc, 0,0,0);\
        acc = __builtin_amdgcn_mfma_f32_16x16x32_bf16(ah, bl, acc, 0,0,0);\
        acc = __builtin_amdgcn_mfma_f32_16x16x32_bf16(al, bh, acc, 0,0,0);\
    } } while (0)

    LOADG(g0, 0);
    WRITEB(0, g0);
    LOADG(g1, 1);
    __syncthreads();

#pragma unroll
    for (int c = 0; c < 16; ++c) {
        if (c + 1 < 16) {
            if ((c + 1) & 1) WRITEB(1, g1); else WRITEB(0, g0);
        }
        if (c + 2 < 16) {
            if (c & 1) LOADG(g1, c + 2); else LOADG(g0, c + 2);
        }
        COMPUTE(c & 1);
        __syncthreads();
    }
#undef LOADG
#undef WRITEB
#undef COMPUTE

    const int col = nt * 64 + w * 16 + lr;
#pragma unroll
    for (int rr = 0; rr < 4; ++rr) {
        const int row = mt * 16 + lk * 4 + rr;
        out[((size_t)(b * QL_ + row)) * KS_ + col] = acc[rr];
    }
}

extern "C" void kernel_launch(void* const* d_in, const int* in_sizes, int n_in,
                              void* d_out, int out_size, void* d_ws, size_t ws_size,
                              hipStream_t stream) {
    const float* query  = (const float*)d_in[0];
    const float* memory = (const float*)d_in[1];
    const unsigned char* mask = (const unsigned char*)d_in[2];
    const float* Wq = (const float*)d_in[3];
    const float* bq = (const float*)d_in[4];
    const float* Wk = (const float*)d_in[5];
    const float* bk = (const float*)d_in[6];
    const float* wl = (const float*)d_in[7];
    // d_in[8] (bl) cancels under softmax shift-invariance; not read.

    float* ws = (float*)d_ws;
    float* Eq = ws + QP_OFF;
    float* Ek = ws + KP_OFF;
    unsigned char* mcan = (unsigned char*)(ws + MASK_OFF);
    unsigned short* Whi  = (unsigned short*)(ws + WH_OFF);
    unsigned short* Wlo  = (unsigned short*)(ws + WL_OFF);
    unsigned short* MThi = (unsigned short*)(ws + MT_H_OFF);
    unsigned short* MTlo = (unsigned short*)(ws + MT_L_OFF);
    unsigned short* Wbhi = (unsigned short*)(ws + WB_H_OFF);
    unsigned short* Wblo = (unsigned short*)(ws + WB_L_OFF);
    unsigned short* Xhi  = (unsigned short*)(ws + XH_OFF);
    unsigned short* Xlo  = (unsigned short*)(ws + XL_OFF);
    float* wlp = ws + WLP_OFF;

    float* attns = (float*)d_out;                      // [B][QL][KS]
    float* wout  = (float*)d_out + B_ * QL_ * KS_;     // [B][QL][ML] (also sr scratch)

    prep_kernel<<<dim3(1217), dim3(256), 0, stream>>>(query, memory, Wq, Wk, wl,
                                                      Whi, Wlo, Xhi, Xlo, mask, mcan, wlp);
    proj_kernel<<<dim3(1152), dim3(256), 0, stream>>>(Xhi, Xlo, Whi, Wlo,
                                                      bq, bk, Eq, Ek);
    logits_kernel<<<dim3(2048), dim3(256), 0, stream>>>(Eq, Ek, wlp, wout,
                                                        memory, MThi, MTlo);
    softmax_kernel<<<dim3(B_ * QL_), dim3(256), 0, stream>>>(wout, mcan, Wbhi, Wblo);
    attn_out_kernel<<<dim3(512), dim3(256), 0, stream>>>(Wbhi, Wblo, MThi, MTlo, attns);
}

// Round 12
// 153.921 us; speedup vs baseline: 1.0463x; 1.0172x over previous
//
#include <hip/hip_runtime.h>

#define B_  8
#define QL_ 128
#define ML_ 1024
#define KS_ 512
#define H_  256

// ws layout (floats):
//   Eq (h-PERMUTED) [B][QL][H]            @ 0        (262144)
//   Ek (h-PERMUTED) [B][ML][H]            @ 262144   (2097152)
//   mask canonical uint8 [B*ML]           @ 2359296  (2048 float slots)
//   Whi bf16 [512][512]                   @ 2361344  (131072)
//   Wlo bf16 [512][512]                   @ 2492416  (131072)
//   MThi bf16 [8][512][1024] (memory^T)   @ 2623488  (2097152)
//   MTlo bf16 [8][512][1024]              @ 4720640  (2097152)
//   Wbhi bf16 [8][128][1024] (weights)    @ 6817792  (524288)
//   Wblo bf16 [8][128][1024]              @ 7342080  (524288)
//   Xhi bf16 [9216][512] (query|memory)   @ 7866368  (2359296)
//   Xlo bf16 [9216][512]                  @ 10225664 (2359296)
//   wlp (h-PERMUTED wl) [256]             @ 12584960 (256)
// h-permutation (within each 8-group): orig o -> ((o&3)<<1)|(o>>2): pairs are
// (h_j, h_{j+4}) -> packed-f32 (v_pk_fma_f32) processing of 2 rcp-quads.
#define QP_OFF 0
#define KP_OFF 262144
#define MASK_OFF 2359296
#define WH_OFF 2361344
#define WL_OFF 2492416
#define MT_H_OFF 2623488
#define MT_L_OFF 4720640
#define WB_H_OFF 6817792
#define WB_L_OFF 7342080
#define XH_OFF 7866368
#define XL_OFF 10225664
#define WLP_OFF 12584960

typedef __attribute__((ext_vector_type(8))) short bfrag;   // 8 bf16 (4 VGPR)
typedef __attribute__((ext_vector_type(4))) float f4acc;   // MFMA acc
typedef __attribute__((ext_vector_type(2))) float f2;      // packed f32 pair

// fp32 -> (hi,lo) bf16 split. hi = truncation (residual <= 2^-8|x|, captured
// exactly by fp32 subtract); lo = RNE of residual (final err <= 2^-17|x|).
__device__ __forceinline__ void split1(float v, unsigned& h, unsigned& lo) {
    unsigned u  = __float_as_uint(v);
    unsigned hb = u & 0xFFFF0000u;
    float    lf = v - __uint_as_float(hb);           // exact
    unsigned ul = __float_as_uint(lf);
    unsigned lr = ul + 0x7FFFu + ((ul >> 16) & 1u);  // RNE
    h  = u >> 16;
    lo = lr >> 16;
}

__device__ __forceinline__ void split4(const float4& a, unsigned& h01, unsigned& h23,
                                       unsigned& l01, unsigned& l23) {
    unsigned h[4], l[4];
    split1(a.x, h[0], l[0]); split1(a.y, h[1], l[1]);
    split1(a.z, h[2], l[2]); split1(a.w, h[3], l[3]);
    h01 = h[0] | (h[1] << 16); h23 = h[2] | (h[3] << 16);
    l01 = l[0] | (l[1] << 16); l23 = l[2] | (l[3] << 16);
}

// ---------------------------------------------------------------------------
// Prep kernel, grid 1217 x 256. The memory-transpose-split (MT) lives in the
// logits launch: MT is only consumed by attn_out (2 launches later), and
// logits is compute-bound — MT's ~50 MB of HBM traffic hides under logits'
// VALU time instead of serializing here.
//   bid 0..63     : W split (Wq rows 0..255, Wk rows 256..511 of Whi/Wlo)
//   bid 64..191   : query  -> Xhi/Xlo rows 0..1023
//   bid 192..1215 : memory -> Xhi/Xlo rows 1024..9215
//   bid 1216      : mask canonicalizer + permuted-wl copy
// ---------------------------------------------------------------------------
__global__ __launch_bounds__(256) void prep_kernel(
    const float* __restrict__ query, const float* __restrict__ memory,
    const float* __restrict__ Wq, const float* __restrict__ Wk,
    const float* __restrict__ wl,
    unsigned short* __restrict__ Whi, unsigned short* __restrict__ Wlo,
    unsigned short* __restrict__ Xhi, unsigned short* __restrict__ Xlo,
    const unsigned char* __restrict__ mraw, unsigned char* __restrict__ mout,
    float* __restrict__ wlp) {
    const int bid = blockIdx.x;
    const int t = threadIdx.x;

    if (bid == 1216) {   // ---- mask canonicalizer + wl permute ----
        wlp[(t & ~7) | (((t & 3) << 1) | ((t >> 2) & 1))] = wl[t];
        __shared__ int s_not01, s_not0f;
        const unsigned int* w = (const unsigned int*)mraw;
        if (t == 0) { s_not01 = 0; s_not0f = 0; }
        __syncthreads();
        int not01 = 0, not0f = 0;
        for (int i = t; i < 2048; i += 256) {
            unsigned int v = w[i];
            if (v != 0u && v != 1u) not01 = 1;
            if (v != 0u && v != 0x3F800000u) not0f = 1;
        }
        if (not01) atomicOr(&s_not01, 1);
        if (not0f) atomicOr(&s_not0f, 1);
        __syncthreads();
        int wordTyped = (!s_not01) || (!s_not0f);
        for (int i = t; i < B_ * ML_; i += 256) {
            unsigned char mv;
            if (wordTyped) mv = (w[i] != 0u) ? 1 : 0;
            else           mv = mraw[i] ? 1 : 0;
            mout[i] = mv;
        }
        return;
    }

    // ---- linear hi/lo splits: W planes and X planes ----
    const float* src; unsigned short *dh, *dl; size_t soff, doff;
    if (bid < 64) {
        src = (bid < 32) ? Wq : Wk;
        soff = (size_t)(bid & 31) * 4096;
        doff = ((bid < 32) ? 0 : 131072) + soff;
        dh = Whi; dl = Wlo;
    } else if (bid < 192) {
        src = query;  soff = (size_t)(bid - 64) * 4096;  doff = soff;
        dh = Xhi; dl = Xlo;
    } else {
        src = memory; soff = (size_t)(bid - 192) * 4096; doff = 524288 + soff;
        dh = Xhi; dl = Xlo;
    }
    soff += (size_t)t * 16; doff += (size_t)t * 16;

    unsigned hw[8], lw[8];
#pragma unroll
    for (int i = 0; i < 4; ++i) {
        float4 v = *(const float4*)(src + soff + i * 4);
        split4(v, hw[i * 2], hw[i * 2 + 1], lw[i * 2], lw[i * 2 + 1]);
    }
    *(uint4*)(dh + doff)     = make_uint4(hw[0], hw[1], hw[2], hw[3]);
    *(uint4*)(dh + doff + 8) = make_uint4(hw[4], hw[5], hw[6], hw[7]);
    *(uint4*)(dl + doff)     = make_uint4(lw[0], lw[1], lw[2], lw[3]);
    *(uint4*)(dl + doff + 8) = make_uint4(lw[4], lw[5], lw[6], lw[7]);
}

// ---------------------------------------------------------------------------
// Projection via bf16x3-split MFMA — validated in R7's win, unchanged since.
// attn_out-style schedule: pre-split operands, BK=64, 1 barrier/chunk,
// reg-prefetch 2 chunks ahead, XOR-swizzled LDS. Stores h-PERMUTED Eq/Ek.
// ---------------------------------------------------------------------------
__global__ __launch_bounds__(256) void proj_kernel(
    const unsigned short* __restrict__ Xhi, const unsigned short* __restrict__ Xlo,
    const unsigned short* __restrict__ Whi, const unsigned short* __restrict__ Wlo,
    const float* __restrict__ bq, const float* __restrict__ bk,
    float* __restrict__ Eq, float* __restrict__ Ek) {
    const int bid = blockIdx.x;
    const int t = threadIdx.x;
    const int wk = (bid & 7) * 144 + (bid >> 3);   // XCD-chunked (1152 = 8*144)
    const int nt = wk & 3;
    const int mt = wk >> 2;          // 0..287

    const bool isQ = (mt < 32);
    const int arow0 = mt * 32;
    const int orow0 = isQ ? arow0 : arow0 - 1024;
    const float* bias = isQ ? bq : bk;
    float* out = isQ ? Eq : Ek;
    const int wrb = (isQ ? 0 : 256) + nt * 64;

    const int w  = t >> 6;
    const int wm = w >> 1, wn = w & 1;   // wave = 16m x 32n
    const int l  = t & 63;
    const int lr = l & 15, lk = l >> 4;

    __shared__ unsigned short As[2][2][32][64];   // [buf][plane][row][k]
    __shared__ unsigned short Bs[2][2][64][64];

    const int pa   = t >> 7;
    const int slot = t & 127;
    const int arow = slot >> 2, ao = slot & 3;
    const int brow = slot >> 1, bo0 = (slot & 1) * 4;
    const unsigned short* asrc = (pa ? Xlo : Xhi) + (size_t)(arow0 + arow) * 512 + ao * 8;
    const unsigned short* bsrc = (pa ? Wlo : Whi) + (size_t)(wrb + brow) * 512 + bo0 * 8;
    const int awd0 = (ao ^ (arow & 7)) * 8;
    const int awd1 = ((ao + 4) ^ (arow & 7)) * 8;
    int bwd[4];
#pragma unroll
    for (int i = 0; i < 4; ++i) bwd[i] = ((bo0 + i) ^ (brow & 7)) * 8;

    f4acc acc[2];
    acc[0] = (f4acc){0.f, 0.f, 0.f, 0.f};
    acc[1] = (f4acc){0.f, 0.f, 0.f, 0.f};

    uint4 g0a0, g0a1, g0b0, g0b1, g0b2, g0b3;
    uint4 g1a0, g1a1, g1b0, g1b1, g1b2, g1b3;

#define LOADG(G, c) do {                                                  \
    G##a0 = *(const uint4*)(asrc + (size_t)(c) * 64);                     \
    G##a1 = *(const uint4*)(asrc + (size_t)(c) * 64 + 32);                \
    G##b0 = *(const uint4*)(bsrc + (size_t)(c) * 64);                     \
    G##b1 = *(const uint4*)(bsrc + (size_t)(c) * 64 + 8);                 \
    G##b2 = *(const uint4*)(bsrc + (size_t)(c) * 64 + 16);                \
    G##b3 = *(const uint4*)(bsrc + (size_t)(c) * 64 + 24); } while (0)

#define WRITEB(P, G) do {                                                 \
    *(uint4*)(&As[P][pa][arow][awd0])  = G##a0;                           \
    *(uint4*)(&As[P][pa][arow][awd1])  = G##a1;                           \
    *(uint4*)(&Bs[P][pa][brow][bwd[0]]) = G##b0;                          \
    *(uint4*)(&Bs[P][pa][brow][bwd[1]]) = G##b1;                          \
    *(uint4*)(&Bs[P][pa][brow][bwd[2]]) = G##b2;                          \
    *(uint4*)(&Bs[P][pa][brow][bwd[3]]) = G##b3; } while (0)

#define COMPUTE(P) do {                                                   \
    _Pragma("unroll")                                                     \
    for (int ks = 0; ks < 2; ++ks) {                                      \
        const int ra = wm * 16 + lr;                                      \
        const int koA = ((ks * 4 + lk) ^ (ra & 7)) * 8;                   \
        bfrag ah = *(const bfrag*)&As[P][0][ra][koA];                     \
        bfrag al = *(const bfrag*)&As[P][1][ra][koA];                     \
        _Pragma("unroll")                                                 \
        for (int ni = 0; ni < 2; ++ni) {                                  \
            const int rb = wn * 32 + ni * 16 + lr;                        \
            const int koB = ((ks * 4 + lk) ^ (rb & 7)) * 8;               \
            bfrag bh = *(const bfrag*)&Bs[P][0][rb][koB];                 \
            bfrag bl = *(const bfrag*)&Bs[P][1][rb][koB];                 \
            acc[ni] = __builtin_amdgcn_mfma_f32_16x16x32_bf16(            \
                ah, bh, acc[ni], 0, 0, 0);                                \
            acc[ni] = __builtin_amdgcn_mfma_f32_16x16x32_bf16(            \
                ah, bl, acc[ni], 0, 0, 0);                                \
            acc[ni] = __builtin_amdgcn_mfma_f32_16x16x32_bf16(            \
                al, bh, acc[ni], 0, 0, 0);                                \
        }                                                                 \
    } } while (0)

    LOADG(g0, 0);
    WRITEB(0, g0);
    LOADG(g1, 1);
    __syncthreads();

#pragma unroll
    for (int c = 0; c < 8; ++c) {
        if (c + 1 < 8) {
            if ((c + 1) & 1) WRITEB(1, g1); else WRITEB(0, g0);
        }
        if (c + 2 < 8) {
            if (c & 1) LOADG(g1, c + 2); else LOADG(g0, c + 2);
        }
        COMPUTE(c & 1);
        __syncthreads();
    }
#undef LOADG
#undef WRITEB
#undef COMPUTE

    const float SC = 2.885390081777926815f;   // 2*log2(e)
#pragma unroll
    for (int ni = 0; ni < 2; ++ni) {
        const int col = nt * 64 + wn * 32 + ni * 16 + lr;   // original h
        const int colp = (col & ~7) | (((col & 3) << 1) | ((col >> 2) & 1));
        const float bc = bias[col];
#pragma unroll
        for (int rr = 0; rr < 4; ++rr) {
            const int row = orow0 + wm * 16 + lk * 4 + rr;
            out[(size_t)row * 256 + colp] =
                __builtin_amdgcn_exp2f(SC * (acc[ni][rr] + bc));
        }
    }
}

// ---------------------------------------------------------------------------
// logits launch, grid 2048:
//   bid 0..1023   : logits (4 q-rows/thread packed-f32 math)
//   bid 1024..2047: memory transpose-split -> MThi/MTlo (BW-bound MT
//                   overlaps compute-bound logits blocks)
// ---------------------------------------------------------------------------
__device__ __forceinline__ f2 qterm8(const float4 k4a, const float4 k4b,
                                     const float4 q4a, const float4 q4b,
                                     const float4 w4a, const float4 w4b,
                                     f2 acc) {
    f2 kp0 = {k4a.x, k4a.y}, kp1 = {k4a.z, k4a.w};
    f2 kp2 = {k4b.x, k4b.y}, kp3 = {k4b.z, k4b.w};
    f2 qp0 = {q4a.x, q4a.y}, qp1 = {q4a.z, q4a.w};
    f2 qp2 = {q4b.x, q4b.y}, qp3 = {q4b.z, q4b.w};
    f2 wp0 = {w4a.x, w4a.y}, wp1 = {w4a.z, w4a.w};
    f2 wp2 = {w4b.x, w4b.y}, wp3 = {w4b.z, w4b.w};
    const f2 one2 = {1.0f, 1.0f};
    f2 pp0 = __builtin_elementwise_fma(kp0, qp0, one2);
    f2 pp1 = __builtin_elementwise_fma(kp1, qp1, one2);
    f2 pp2 = __builtin_elementwise_fma(kp2, qp2, one2);
    f2 pp3 = __builtin_elementwise_fma(kp3, qp3, one2);
    f2 p01 = pp0 * pp1, p23 = pp2 * pp3;
    f2 n01 = __builtin_elementwise_fma(wp1, pp0, wp0 * pp1);
    f2 n23 = __builtin_elementwise_fma(wp3, pp2, wp2 * pp3);
    f2 Nm  = __builtin_elementwise_fma(n23, p01, n01 * p23);
    f2 P   = p01 * p23;
    f2 r   = {__builtin_amdgcn_rcpf(P.x), __builtin_amdgcn_rcpf(P.y)};
    return __builtin_elementwise_fma(Nm, r, acc);
}

__global__ __launch_bounds__(256) void logits_kernel(
    const float* __restrict__ Eq, const float* __restrict__ Ek,
    const float* __restrict__ wlp, float* __restrict__ sr,
    const float* __restrict__ memory,
    unsigned short* __restrict__ MThi, unsigned short* __restrict__ MTlo) {
    const int tid = threadIdx.x;
    __shared__ __align__(16) unsigned char smem[17408];   // union: kq | T

    if (blockIdx.x >= 1024) {   // ---- memory transpose-split (64x64 tile) ----
        float (*T)[68] = (float(*)[68])smem;              // [64][68]
        const int idx = blockIdx.x - 1024;   // 0..1023
        const int b  = idx >> 7;
        const int r  = idx & 127;
        const int mt = r >> 3;
        const int st = r & 7;

        const int i  = tid >> 2, jb = (tid & 3) << 4;
        const float* mp = memory + ((size_t)(b * ML_ + mt * 64 + i)) * KS_ + st * 64 + jb;
#pragma unroll
        for (int q = 0; q < 4; ++q)
            *(float4*)(&T[i][jb + q * 4]) = *(const float4*)(mp + q * 4);
        __syncthreads();

        const int s = tid >> 2, mb = (tid & 3) << 4;
        unsigned hh[16], ll[16];
#pragma unroll
        for (int e = 0; e < 16; ++e) split1(T[mb + e][s], hh[e], ll[e]);
        unsigned hp[8], lp[8];
#pragma unroll
        for (int e = 0; e < 8; ++e) {
            hp[e] = hh[2 * e] | (hh[2 * e + 1] << 16);
            lp[e] = ll[2 * e] | (ll[2 * e + 1] << 16);
        }
        const size_t doff = ((size_t)(b * KS_ + st * 64 + s)) * ML_ + mt * 64 + mb;
        *(uint4*)(MThi + doff)     = make_uint4(hp[0], hp[1], hp[2], hp[3]);
        *(uint4*)(MThi + doff + 8) = make_uint4(hp[4], hp[5], hp[6], hp[7]);
        *(uint4*)(MTlo + doff)     = make_uint4(lp[0], lp[1], lp[2], lp[3]);
        *(uint4*)(MTlo + doff + 8) = make_uint4(lp[4], lp[5], lp[6], lp[7]);
        return;
    }

    // ---- logits ----
    float (*kq)[8][64][4] = (float(*)[8][64][4])smem;     // [2][8][64][4]
    const int bid = blockIdx.x;
    const int b  = bid & 7;
    const int r2 = bid >> 3;
    const int mt = r2 & 15;     // m tile of 64
    const int qt = r2 >> 4;     // q 16-group (0..7)
    const int m  = tid & 63;
    const int qh = __builtin_amdgcn_readfirstlane(tid >> 6);  // 0..3, wave-uniform

    const float* q0 = Eq + ((size_t)(b * QL_ + qt * 16 + qh * 4)) * H_;  // 4 q rows
    const float* kpb = Ek + ((size_t)(b * ML_ + mt * 64)) * H_;

    const int srow = tid & 63;
    const int sq   = tid >> 6;           // 0..3
    const float* kst = kpb + (size_t)srow * H_ + 8 * sq;

    float4 a0 = *(const float4*)(kst);
    float4 a1 = *(const float4*)(kst + 4);
    *(float4*)(&kq[0][2 * sq + 0][srow][0]) = a0;
    *(float4*)(&kq[0][2 * sq + 1][srow][0]) = a1;
    a0 = *(const float4*)(kst + 32);
    a1 = *(const float4*)(kst + 36);
    __syncthreads();

    f2 accp[4];
#pragma unroll
    for (int j = 0; j < 4; ++j) accp[j] = (f2){0.f, 0.f};

    for (int c = 0; c < 8; ++c) {
        const int cb = c & 1;
        if (c < 7) {                        // stage chunk c+1 into other buf
            *(float4*)(&kq[cb ^ 1][2 * sq + 0][srow][0]) = a0;
            *(float4*)(&kq[cb ^ 1][2 * sq + 1][srow][0]) = a1;
            if (c < 6) {                    // prefetch chunk c+2 (2 ahead)
                a0 = *(const float4*)(kst + (c + 2) * 32);
                a1 = *(const float4*)(kst + (c + 2) * 32 + 4);
            }
        }
        const int h0 = c * 32;
#pragma unroll
        for (int pg = 0; pg < 4; ++pg) {
            float4 k4a = *(const float4*)(&kq[cb][2 * pg + 0][m][0]);
            float4 k4b = *(const float4*)(&kq[cb][2 * pg + 1][m][0]);
            float4 w4a = *(const float4*)(wlp + h0 + pg * 8);
            float4 w4b = *(const float4*)(wlp + h0 + pg * 8 + 4);
#pragma unroll
            for (int j = 0; j < 4; ++j) {
                float4 q4a = *(const float4*)(q0 + (size_t)j * H_ + h0 + pg * 8);
                float4 q4b = *(const float4*)(q0 + (size_t)j * H_ + h0 + pg * 8 + 4);
                accp[j] = qterm8(k4a, k4b, q4a, q4b, w4a, w4b, accp[j]);
            }
        }
        __syncthreads();
    }
    const size_t ro = ((size_t)(b * QL_ + qt * 16 + qh * 4)) * ML_ + mt * 64 + m;
#pragma unroll
    for (int j = 0; j < 4; ++j)
        sr[ro + (size_t)j * ML_] = accp[j].x + accp[j].y;
}

// ---------------------------------------------------------------------------
// In-place masked softmax + bf16 hi/lo split of weights for the MFMA
// attn_out (A-operand). logits_eff = -2*sr (shift-invariant).
// ---------------------------------------------------------------------------
__global__ __launch_bounds__(256) void softmax_kernel(
    float* __restrict__ wrow_io, const unsigned char* __restrict__ mv,
    unsigned short* __restrict__ Wbhi, unsigned short* __restrict__ Wblo) {
    const int row = blockIdx.x;
    const int b = row >> 7;
    const int tid = threadIdx.x;
    float* srow = wrow_io + (size_t)row * ML_;
    const unsigned char* mrow = mv + b * ML_;
    __shared__ float red[4];

    float4 s4 = *(const float4*)(srow + tid * 4);
    uchar4 m4 = *(const uchar4*)(mrow + tid * 4);
    float l[4];
    l[0] = m4.x ? -1e18f : -2.0f * s4.x;
    l[1] = m4.y ? -1e18f : -2.0f * s4.y;
    l[2] = m4.z ? -1e18f : -2.0f * s4.z;
    l[3] = m4.w ? -1e18f : -2.0f * s4.w;

    float mx = fmaxf(fmaxf(l[0], l[1]), fmaxf(l[2], l[3]));
#pragma unroll
    for (int off = 32; off >= 1; off >>= 1)
        mx = fmaxf(mx, __shfl_xor(mx, off));
    if ((tid & 63) == 0) red[tid >> 6] = mx;
    __syncthreads();
    mx = fmaxf(fmaxf(red[0], red[1]), fmaxf(red[2], red[3]));
    __syncthreads();

    const float L2E = 1.44269504088896340736f;
    float e[4], s = 0.f;
#pragma unroll
    for (int i = 0; i < 4; ++i) {
        e[i] = __builtin_amdgcn_exp2f((l[i] - mx) * L2E);
        s += e[i];
    }
#pragma unroll
    for (int off = 32; off >= 1; off >>= 1)
        s += __shfl_xor(s, off);
    if ((tid & 63) == 0) red[tid >> 6] = s;
    __syncthreads();
    s = (red[0] + red[1]) + (red[2] + red[3]);
    float inv = __builtin_amdgcn_rcpf(s);
    float4 o = make_float4(e[0] * inv, e[1] * inv, e[2] * inv, e[3] * inv);
    *(float4*)(srow + tid * 4) = o;

    unsigned h01, h23, l01, l23;
    split4(o, h01, h23, l01, l23);
    *(uint2*)(Wbhi + (size_t)row * ML_ + tid * 4) = make_uint2(h01, h23);
    *(uint2*)(Wblo + (size_t)row * ML_ + tid * 4) = make_uint2(l01, l23);
}

// ---------------------------------------------------------------------------
// attns[b] = weights[b] (128x1024) @ memory[b] (1024x512), bf16x3 MFMA.
// (validated-fast schedule from R6)
// ---------------------------------------------------------------------------
__global__ __launch_bounds__(256) void attn_out_kernel(
    const unsigned short* __restrict__ Wbhi, const unsigned short* __restrict__ Wblo,
    const unsigned short* __restrict__ MThi, const unsigned short* __restrict__ MTlo,
    float* __restrict__ out) {
    const int bid = blockIdx.x;
    const int b  = bid & 7;
    const int r  = bid >> 3;          // 0..63
    const int mt = r & 7;             // m tile of 16
    const int nt = r >> 3;            // n tile of 64
    const int t = threadIdx.x;
    const int w  = t >> 6;
    const int l  = t & 63;
    const int lr = l & 15, lk = l >> 4;

    __shared__ unsigned short As[2][16][2][64];   // [buf][row][plane][k]
    __shared__ unsigned short Bs[2][64][2][64];

    const int pa  = t >> 7;
    const int ar  = (t >> 3) & 15;
    const int acq = t & 7;
    const unsigned short* asrc = (pa ? Wblo : Wbhi)
        + ((size_t)(b * QL_ + mt * 16 + ar)) * ML_ + acq * 8;
    const int aws = (acq ^ (ar & 7)) * 8;

    const int pb  = t >> 7;
    const int br  = (t & 127) >> 1;
    const int bq0 = (t & 1) * 4;
    const unsigned short* bsrc = (pb ? MTlo : MThi)
        + ((size_t)(b * KS_ + nt * 64 + br)) * ML_ + bq0 * 8;
    int bws[4];
#pragma unroll
    for (int i2 = 0; i2 < 4; ++i2) bws[i2] = ((bq0 + i2) ^ (br & 7)) * 8;

    f4acc acc = (f4acc){0.f, 0.f, 0.f, 0.f};

    uint4 g0a, g0b0, g0b1, g0b2, g0b3;
    uint4 g1a, g1b0, g1b1, g1b2, g1b3;

#define LOADG(G, c) do {                                                  \
    G##a  = *(const uint4*)(asrc + (size_t)(c) * 64);                     \
    G##b0 = *(const uint4*)(bsrc + (size_t)(c) * 64);                     \
    G##b1 = *(const uint4*)(bsrc + (size_t)(c) * 64 + 8);                 \
    G##b2 = *(const uint4*)(bsrc + (size_t)(c) * 64 + 16);                \
    G##b3 = *(const uint4*)(bsrc + (size_t)(c) * 64 + 24); } while (0)

#define WRITEB(P, G) do {                                                 \
    *(uint4*)(&As[P][ar][pa][aws])    = G##a;                             \
    *(uint4*)(&Bs[P][br][pb][bws[0]]) = G##b0;                            \
    *(uint4*)(&Bs[P][br][pb][bws[1]]) = G##b1;                            \
    *(uint4*)(&Bs[P][br][pb][bws[2]]) = G##b2;                            \
    *(uint4*)(&Bs[P][br][pb][bws[3]]) = G##b3; } while (0)

#define COMPUTE(P) do {                                                   \
    _Pragma("unroll")                                                     \
    for (int ks = 0; ks < 2; ++ks) {                                      \
        const int k8 = (ks * 4 + lk) ^ (lr & 7);                          \
        bfrag ah = *(const bfrag*)&As[P][lr][0][k8 * 8];                  \
        bfrag al = *(const bfrag*)&As[P][lr][1][k8 * 8];                  \
        bfrag bh = *(const bfrag*)&Bs[P][w * 16 + lr][0][k8 * 8];         \
        bfrag bl = *(const bfrag*)&Bs[P][w * 16 + lr][1][k8 * 8];         \
        acc = __builtin_amdgcn_mfma_f32_16x16x32_bf16(ah, bh, acc, 0,0,0);\
        acc = __builtin_amdgcn_mfma_f32_16x16x32_bf16(ah, bl, acc, 0,0,0);\
        acc = __builtin_amdgcn_mfma_f32_16x16x32_bf16(al, bh, acc, 0,0,0);\
    } } while (0)

    LOADG(g0, 0);
    WRITEB(0, g0);
    LOADG(g1, 1);
    __syncthreads();

#pragma unroll
    for (int c = 0; c < 16; ++c) {
        if (c + 1 < 16) {
            if ((c + 1) & 1) WRITEB(1, g1); else WRITEB(0, g0);
        }
        if (c + 2 < 16) {
            if (c & 1) LOADG(g1, c + 2); else LOADG(g0, c + 2);
        }
        COMPUTE(c & 1);
        __syncthreads();
    }
#undef LOADG
#undef WRITEB
#undef COMPUTE

    const int col = nt * 64 + w * 16 + lr;
#pragma unroll
    for (int rr = 0; rr < 4; ++rr) {
        const int row = mt * 16 + lk * 4 + rr;
        out[((size_t)(b * QL_ + row)) * KS_ + col] = acc[rr];
    }
}

extern "C" void kernel_launch(void* const* d_in, const int* in_sizes, int n_in,
                              void* d_out, int out_size, void* d_ws, size_t ws_size,
                              hipStream_t stream) {
    const float* query  = (const float*)d_in[0];
    const float* memory = (const float*)d_in[1];
    const unsigned char* mask = (const unsigned char*)d_in[2];
    const float* Wq = (const float*)d_in[3];
    const float* bq = (const float*)d_in[4];
    const float* Wk = (const float*)d_in[5];
    const float* bk = (const float*)d_in[6];
    const float* wl = (const float*)d_in[7];
    // d_in[8] (bl) cancels under softmax shift-invariance; not read.

    float* ws = (float*)d_ws;
    float* Eq = ws + QP_OFF;
    float* Ek = ws + KP_OFF;
    unsigned char* mcan = (unsigned char*)(ws + MASK_OFF);
    unsigned short* Whi  = (unsigned short*)(ws + WH_OFF);
    unsigned short* Wlo  = (unsigned short*)(ws + WL_OFF);
    unsigned short* MThi = (unsigned short*)(ws + MT_H_OFF);
    unsigned short* MTlo = (unsigned short*)(ws + MT_L_OFF);
    unsigned short* Wbhi = (unsigned short*)(ws + WB_H_OFF);
    unsigned short* Wblo = (unsigned short*)(ws + WB_L_OFF);
    unsigned short* Xhi  = (unsigned short*)(ws + XH_OFF);
    unsigned short* Xlo  = (unsigned short*)(ws + XL_OFF);
    float* wlp = ws + WLP_OFF;

    float* attns = (float*)d_out;                      // [B][QL][KS]
    float* wout  = (float*)d_out + B_ * QL_ * KS_;     // [B][QL][ML] (also sr scratch)

    prep_kernel<<<dim3(1217), dim3(256), 0, stream>>>(query, memory, Wq, Wk, wl,
                                                      Whi, Wlo, Xhi, Xlo, mask, mcan, wlp);
    proj_kernel<<<dim3(1152), dim3(256), 0, stream>>>(Xhi, Xlo, Whi, Wlo,
                                                      bq, bk, Eq, Ek);
    logits_kernel<<<dim3(2048), dim3(256), 0, stream>>>(Eq, Ek, wlp, wout,
                                                        memory, MThi, MTlo);
    softmax_kernel<<<dim3(B_ * QL_), dim3(256), 0, stream>>>(wout, mcan, Wbhi, Wblo);
    attn_out_kernel<<<dim3(512), dim3(256), 0, stream>>>(Wbhi, Wblo, MThi, MTlo, attns);
}